// Round 2
// baseline (188.136 us; speedup 1.0000x reference)
//
#include <hip/hip_runtime.h>
#include <hip/hip_bf16.h>
#include <stdint.h>

#define BTOT 4096
#define RR   64
#define DIMD 128
#define NB   8
#define NBLK (BTOT / NB)   /* 512 blocks */

typedef short s16x8 __attribute__((ext_vector_type(8)));
typedef float f32x4 __attribute__((ext_vector_type(4)));

__device__ __forceinline__ unsigned short f2bf(float x) {
  __hip_bfloat16 h = __float2bfloat16(x);
  return __builtin_bit_cast(unsigned short, h);
}
__device__ __forceinline__ float bf2f(unsigned short u) {
  unsigned int v = ((unsigned int)u) << 16;
  return __builtin_bit_cast(float, v);
}

// ---------------------------------------------------------------------------
// Pre-kernel: qproj[b,k] = sum_d query_r[b,d]*W1[k,128+d] + b1[k]  (fp32),
// offset_emb passthrough into out[BTOT*DIMD ...], and blocks 0/1 emit
// XOR-swizzled bf16 copies of W1a / W2 into ws.
// Swizzle: element (k,d) stored at k*128 + (d ^ ((k&7)<<3)).
// ---------------------------------------------------------------------------
__global__ __launch_bounds__(256) void prep_kernel(
    const float* __restrict__ W1, const float* __restrict__ b1,
    const float* __restrict__ query_r, const float* __restrict__ W2,
    const float* __restrict__ offset_emb,
    float* __restrict__ qproj, unsigned short* __restrict__ w1a_swz,
    unsigned short* __restrict__ w2_swz, float* __restrict__ out)
{
  __shared__ float w1b[128 * 132];   // +4 pad
  __shared__ float qrs[256];
  const int tid = threadIdx.x;

  { // offset_emb passthrough (1 float4 per thread)
    const size_t ob = (size_t)blockIdx.x * NB * DIMD + (size_t)tid * 4;
    *reinterpret_cast<float4*>(out + (size_t)BTOT * DIMD + ob) =
        *reinterpret_cast<const float4*>(offset_emb + ob);
  }
  { // stage W1b fp32 into padded LDS
    const int k = tid >> 1, d0 = (tid & 1) * 64;
    const float* src = W1 + k * 256 + 128 + d0;
    float* dst = &w1b[k * 132 + d0];
    #pragma unroll
    for (int i = 0; i < 64; i += 4)
      *reinterpret_cast<float4*>(dst + i) = *reinterpret_cast<const float4*>(src + i);
  }
  if (blockIdx.x < 2) { // swizzled bf16 weights
    const float* Wsrc = (blockIdx.x == 0) ? W1 : W2;
    unsigned short* dstw = (blockIdx.x == 0) ? w1a_swz : w2_swz;
    const int stride = (blockIdx.x == 0) ? 256 : 128;
    for (int i = tid; i < 128 * 128; i += 256) {
      const int k = i >> 7, d = i & 127;
      dstw[k * 128 + (d ^ ((k & 7) << 3))] = f2bf(Wsrc[k * stride + d]);
    }
  }
  __syncthreads();

  const int b0 = blockIdx.x * NB;
  const int k = tid & 127, bh = tid >> 7;
  for (int p = 0; p < NB / 2; ++p) {
    const int b = b0 + p * 2;
    qrs[tid] = query_r[(size_t)(b + bh) * DIMD + k];
    __syncthreads();
    float acc = b1[k];
    const float* qq = &qrs[bh * 128];
    const float* wr = &w1b[k * 132];
    #pragma unroll
    for (int d = 0; d < 128; d += 4) {
      float4 wv = *reinterpret_cast<const float4*>(wr + d);
      float4 qv = *reinterpret_cast<const float4*>(qq + d);
      acc = fmaf(wv.x, qv.x, acc); acc = fmaf(wv.y, qv.y, acc);
      acc = fmaf(wv.z, qv.z, acc); acc = fmaf(wv.w, qv.w, acc);
    }
    qproj[(size_t)(b + bh) * DIMD + k] = acc;
    __syncthreads();
  }
}

// ---------------------------------------------------------------------------
// Main kernel: each wave owns 2 whole b's (4 chunks of 16 r-rows each).
// All cross-lane traffic is wave-private LDS -> ZERO barriers in the loop,
// no atomics, deterministic. Depth-1 prefetch of the next chunk's
// refer_r/refer_embs/start_embs (24x16B coalesced loads per lane).
// bias = refer_embs - start_embs - refer_r computed in row layout (registers),
// transposed to C layout through the wave's LDS buffer after GEMM2.
// LDS = 32K (W1a) + 32K (W2) + 4x4K (wave buffers) = 80KB -> 2 blocks/CU.
// ---------------------------------------------------------------------------
__global__ __launch_bounds__(256, 2) void main_kernel(
    const float* __restrict__ query_emb,
    const float* __restrict__ refer_embs, const float* __restrict__ refer_r,
    const float* __restrict__ start_embs, const float* __restrict__ b2,
    const float* __restrict__ qproj, const unsigned short* __restrict__ w1a_swz,
    const unsigned short* __restrict__ w2_swz, float* __restrict__ out)
{
  __shared__ unsigned short lds_w1a[128 * 128];
  __shared__ unsigned short lds_w2[128 * 128];
  __shared__ unsigned short lds_rr[4][16 * 128];

  const int tid  = threadIdx.x;
  const int wave = tid >> 6;
  const int lane = tid & 63;
  const int g    = lane >> 4;   // k-group
  const int c    = lane & 15;   // row/col-in-tile

  { // stage swizzled weights (linear copy; swizzle pre-applied in ws)
    const uint4* s1 = reinterpret_cast<const uint4*>(w1a_swz);
    const uint4* s2 = reinterpret_cast<const uint4*>(w2_swz);
    uint4* d1 = reinterpret_cast<uint4*>(lds_w1a);
    uint4* d2 = reinterpret_cast<uint4*>(lds_w2);
    #pragma unroll
    for (int i = 0; i < 8; ++i) {
      d1[tid + 256 * i] = s1[tid + 256 * i];
      d2[tid + 256 * i] = s2[tid + 256 * i];
    }
  }
  __syncthreads();   // the ONLY barrier

  unsigned short* myrr = &lds_rr[wave][0];
  const int srl  = lane >> 2;          // staging local row 0..15
  const int sd0  = (lane & 3) * 32;    // staging: 32 floats per lane
  const int sw_s = (srl & 7) << 3;
  const int swc  = (c & 7) << 3;       // swizzle for rows c / nt*16+c
  const int rl4  = 4 * g;

  const int b0w = blockIdx.x * NB + wave * 2;  // this wave's first b

  float b2v[8];
  #pragma unroll
  for (int nt = 0; nt < 8; ++nt) b2v[nt] = b2[nt * 16 + c];

  float4 fv[8], ev[8], sv[8];
  float qn[8], qe[8];
  { // prologue: chunk 0 of b0w + qproj/query_emb for b0w
    const size_t base = (size_t)b0w * RR * DIMD + (size_t)srl * DIMD + sd0;
    #pragma unroll
    for (int i = 0; i < 8; ++i) {
      fv[i] = *reinterpret_cast<const float4*>(refer_r    + base + 4 * i);
      ev[i] = *reinterpret_cast<const float4*>(refer_embs + base + 4 * i);
      sv[i] = *reinterpret_cast<const float4*>(start_embs + base + 4 * i);
    }
    #pragma unroll
    for (int nt = 0; nt < 8; ++nt) {
      qn[nt] = qproj[(size_t)b0w * DIMD + nt * 16 + c];
      qe[nt] = query_emb[(size_t)b0w * DIMD + nt * 16 + c];
    }
  }

  float acc[8];
  #pragma unroll
  for (int nt = 0; nt < 8; ++nt) acc[nt] = 0.f;

  #pragma unroll
  for (int it = 0; it < 8; ++it) {           // 2 b's x 4 chunks, fully unrolled
    const int b = b0w + (it >> 2);

    // ---- 1. stage refer_r chunk -> myrr (bf16, swizzled)
    {
      unsigned short* wrow = &myrr[srl * DIMD];
      #pragma unroll
      for (int gi = 0; gi < 4; ++gi) {
        union { unsigned short u[8]; uint4 v; } pk;
        const float4 a = fv[2 * gi], bq = fv[2 * gi + 1];
        pk.u[0] = f2bf(a.x);  pk.u[1] = f2bf(a.y);
        pk.u[2] = f2bf(a.z);  pk.u[3] = f2bf(a.w);
        pk.u[4] = f2bf(bq.x); pk.u[5] = f2bf(bq.y);
        pk.u[6] = f2bf(bq.z); pk.u[7] = f2bf(bq.w);
        *reinterpret_cast<uint4*>(&wrow[(sd0 + gi * 8) ^ sw_s]) = pk.v;
      }
    }

    // ---- 2. bias = ev - sv - fv (row layout), pack bf16 (frees ev/sv/fv)
    uint4 bp[4];
    #pragma unroll
    for (int gi = 0; gi < 4; ++gi) {
      union { unsigned short u[8]; uint4 v; } pk;
      const float4 e0 = ev[2 * gi], s0 = sv[2 * gi], f0 = fv[2 * gi];
      const float4 e1 = ev[2 * gi + 1], s1 = sv[2 * gi + 1], f1 = fv[2 * gi + 1];
      pk.u[0] = f2bf(e0.x - s0.x - f0.x); pk.u[1] = f2bf(e0.y - s0.y - f0.y);
      pk.u[2] = f2bf(e0.z - s0.z - f0.z); pk.u[3] = f2bf(e0.w - s0.w - f0.w);
      pk.u[4] = f2bf(e1.x - s1.x - f1.x); pk.u[5] = f2bf(e1.y - s1.y - f1.y);
      pk.u[6] = f2bf(e1.z - s1.z - f1.z); pk.u[7] = f2bf(e1.w - s1.w - f1.w);
      bp[gi] = pk.v;
    }

    // ---- 3. init GEMM1 accumulators from qproj (frees qn)
    f32x4 Ch[8];
    #pragma unroll
    for (int nt = 0; nt < 8; ++nt) Ch[nt] = (f32x4){qn[nt], qn[nt], qn[nt], qn[nt]};

    // ---- 4. prefetch next chunk (depth-1 pipeline; registers just died)
    if (it + 1 < 8) {
      const int bn = b0w + ((it + 1) >> 2);
      const int rn = ((it + 1) & 3) * 16;
      const size_t base = (size_t)bn * RR * DIMD + (size_t)(rn + srl) * DIMD + sd0;
      #pragma unroll
      for (int i = 0; i < 8; ++i) {
        fv[i] = *reinterpret_cast<const float4*>(refer_r    + base + 4 * i);
        ev[i] = *reinterpret_cast<const float4*>(refer_embs + base + 4 * i);
        sv[i] = *reinterpret_cast<const float4*>(start_embs + base + 4 * i);
      }
    }

    asm volatile("s_waitcnt lgkmcnt(0)" ::: "memory");  // staging visible (wave-local)

    // ---- 5. A-frags + GEMM1: h = refer_r * W1a^T (+ qproj)
    s16x8 af[4];
    #pragma unroll
    for (int ks = 0; ks < 4; ++ks)
      af[ks] = *reinterpret_cast<const s16x8*>(&myrr[c * DIMD + ((ks * 32 + g * 8) ^ swc)]);
    #pragma unroll
    for (int ks = 0; ks < 4; ++ks)
      #pragma unroll
      for (int nt = 0; nt < 8; ++nt) {
        s16x8 bf = *reinterpret_cast<const s16x8*>(
            &lds_w1a[(nt * 16 + c) * DIMD + ((ks * 32 + g * 8) ^ swc)]);
        Ch[nt] = __builtin_amdgcn_mfma_f32_16x16x32_bf16(af[ks], bf, Ch[nt], 0, 0, 0);
      }

    // ---- 6. h (relu, bf16) overwrites wave's LDS slice
    asm volatile("s_waitcnt lgkmcnt(0)" ::: "memory");
    #pragma unroll
    for (int nt = 0; nt < 8; ++nt)
      #pragma unroll
      for (int r = 0; r < 4; ++r) {
        const int rl = rl4 + r;
        myrr[rl * DIMD + ((nt * 16 + c) ^ ((rl & 7) << 3))] = f2bf(fmaxf(Ch[nt][r], 0.f));
      }
    asm volatile("s_waitcnt lgkmcnt(0)" ::: "memory");

    // ---- 7. GEMM2: attn = h * W2^T (+ b2)
    s16x8 hf[4];
    #pragma unroll
    for (int ks = 0; ks < 4; ++ks)
      hf[ks] = *reinterpret_cast<const s16x8*>(&myrr[c * DIMD + ((ks * 32 + g * 8) ^ swc)]);
    f32x4 Ca[8];
    #pragma unroll
    for (int nt = 0; nt < 8; ++nt) Ca[nt] = (f32x4){b2v[nt], b2v[nt], b2v[nt], b2v[nt]};
    #pragma unroll
    for (int ks = 0; ks < 4; ++ks)
      #pragma unroll
      for (int nt = 0; nt < 8; ++nt) {
        s16x8 wf = *reinterpret_cast<const s16x8*>(
            &lds_w2[(nt * 16 + c) * DIMD + ((ks * 32 + g * 8) ^ swc)]);
        Ca[nt] = __builtin_amdgcn_mfma_f32_16x16x32_bf16(hf[ks], wf, Ca[nt], 0, 0, 0);
      }

    // ---- 8. bias -> LDS (row layout; h fully consumed by hf reads, DS in-order)
    {
      unsigned short* wrow = &myrr[srl * DIMD];
      #pragma unroll
      for (int gi = 0; gi < 4; ++gi)
        *reinterpret_cast<uint4*>(&wrow[(sd0 + gi * 8) ^ sw_s]) = bp[gi];
    }
    asm volatile("s_waitcnt lgkmcnt(0)" ::: "memory");

    // ---- 9. bias at C positions, multiply-accumulate, wave-reduce
    #pragma unroll
    for (int nt = 0; nt < 8; ++nt) {
      float s = 0.f;
      #pragma unroll
      for (int r = 0; r < 4; ++r) {
        const int rl = rl4 + r;
        const float bcv = bf2f(myrr[rl * DIMD + ((nt * 16 + c) ^ ((rl & 7) << 3))]);
        s = fmaf(Ca[nt][r], bcv, s);
      }
      s += __shfl_xor(s, 16);
      s += __shfl_xor(s, 32);
      acc[nt] += s;
    }

    // ---- 10. at b boundary: store, reset, fetch next b's qproj/query_emb
    if ((it & 3) == 3) {
      if (lane < 16) {
        #pragma unroll
        for (int nt = 0; nt < 8; ++nt)
          out[(size_t)b * DIMD + nt * 16 + c] = qe[nt] + acc[nt];
      }
      #pragma unroll
      for (int nt = 0; nt < 8; ++nt) acc[nt] = 0.f;
      if (it < 7) {
        #pragma unroll
        for (int nt = 0; nt < 8; ++nt) {
          qn[nt] = qproj[(size_t)(b + 1) * DIMD + nt * 16 + c];
          qe[nt] = query_emb[(size_t)(b + 1) * DIMD + nt * 16 + c];
        }
      }
    }
  }
}

extern "C" void kernel_launch(void* const* d_in, const int* in_sizes, int n_in,
                              void* d_out, int out_size, void* d_ws, size_t ws_size,
                              hipStream_t stream) {
  const float* query_emb  = (const float*)d_in[0];
  const float* offset_emb = (const float*)d_in[1];
  const float* refer_embs = (const float*)d_in[2];
  const float* query_r    = (const float*)d_in[3];
  const float* refer_r    = (const float*)d_in[4];
  const float* start_embs = (const float*)d_in[5];
  const float* W1 = (const float*)d_in[6];
  const float* b1 = (const float*)d_in[7];
  const float* W2 = (const float*)d_in[8];
  const float* b2 = (const float*)d_in[9];
  float* out = (float*)d_out;

  float* qproj = (float*)d_ws;                       // 4096*128 f32 = 2 MB
  unsigned short* w1a_swz =
      (unsigned short*)((char*)d_ws + (size_t)BTOT * DIMD * sizeof(float));
  unsigned short* w2_swz = w1a_swz + 128 * 128;      // +32 KB each

  hipLaunchKernelGGL(prep_kernel, dim3(NBLK), dim3(256), 0, stream,
                     W1, b1, query_r, W2, offset_emb, qproj, w1a_swz, w2_swz, out);
  hipLaunchKernelGGL(main_kernel, dim3(NBLK), dim3(256), 0, stream,
                     query_emb, refer_embs, refer_r, start_embs,
                     b2, qproj, w1a_swz, w2_swz, out);
}